// Round 2
// baseline (10268.080 us; speedup 1.0000x reference)
//
#include <hip/hip_runtime.h>
#include <hip/hip_bf16.h>

typedef __attribute__((ext_vector_type(8))) short shortx8;
typedef __attribute__((ext_vector_type(4))) float floatx4;
typedef unsigned short u16;
typedef unsigned int u32;

#define NGRU 1024
#define NB 128
#define NSTEPS 256

// ---- ws layout (bytes) ----
#define WS_W0   0u           // Wih bf16  [2][3072][1024]
#define WS_WF   12582912u    // fused bf16 [2][4096][1024] (rz fused, in=Wih_n, hn=Whh_n)
#define WS_BIAS 29360128u    // fp32 [2][4][1024]
#define WS_XS   29392896u    // x_spin bf16 [2][128][1024]
#define WS_HBF  29917184u    // h bf16 [4 seq][2 buf][128][1024]
#define WS_BARS 32014336u    // 4 counters, 128B apart

__device__ __forceinline__ float sigm_f(float x) {
  return 1.0f / (1.0f + __expf(-x));
}
__device__ __forceinline__ float tanh_f(float x) {
  float e = __expf(-2.0f * fabsf(x));
  float t = (1.0f - e) / (1.0f + e);
  return copysignf(t, x);
}
__device__ __forceinline__ void store_bf4(__hip_bfloat16* dst, float a, float b, float c, float d) {
  __hip_bfloat16 t[4] = {__float2bfloat16(a), __float2bfloat16(b),
                         __float2bfloat16(c), __float2bfloat16(d)};
  *reinterpret_cast<uint2*>(dst) = *reinterpret_cast<uint2*>(t);
}

// ---------- prep: weights -> bf16 (plain Wih + fused) ----------
__global__ void prep_w(const float* __restrict__ ihU, const float* __restrict__ hhU,
                       const float* __restrict__ ihD, const float* __restrict__ hhD,
                       __hip_bfloat16* __restrict__ Wih_b, __hip_bfloat16* __restrict__ Wf_b) {
  unsigned idx = blockIdx.x * 256u + threadIdx.x;   // < 2*4096*256
  unsigned wset = idx >> 20;
  unsigned rem = idx & 1048575u;
  unsigned j = rem >> 8;                 // row 0..4095 (gate-major: r,z,in,hn)
  unsigned k4 = (rem & 255u) << 2;       // k 0..1020 step 4
  const float* ih = wset ? ihD : ihU;
  const float* hh = wset ? hhD : hhU;
  unsigned g = j >> 10, r = j & 1023u;
  if (j < 3072u) {
    const float* pa = ih + (size_t)j * NGRU + k4;
    float4 a = *(const float4*)pa;
    store_bf4(Wih_b + (size_t)wset * 3072 * NGRU + (size_t)j * NGRU + k4, a.x, a.y, a.z, a.w);
    float fx = a.x, fy = a.y, fz = a.z, fw = a.w;
    if (g < 2u) {
      const float* pb = hh + (size_t)j * NGRU + k4;
      float4 b = *(const float4*)pb;
      fx += b.x; fy += b.y; fz += b.z; fw += b.w;
    }
    store_bf4(Wf_b + (size_t)wset * 4096 * NGRU + (size_t)j * NGRU + k4, fx, fy, fz, fw);
  } else {
    const float* pb = hh + (size_t)(2048u + r) * NGRU + k4;
    float4 b = *(const float4*)pb;
    store_bf4(Wf_b + (size_t)wset * 4096 * NGRU + (size_t)j * NGRU + k4, b.x, b.y, b.z, b.w);
  }
}

// ---------- prep: x_spin -> bf16 ----------
__global__ void prep_x(const float* __restrict__ x, __hip_bfloat16* __restrict__ xs) {
  unsigned idx = blockIdx.x * 256u + threadIdx.x;   // < 2*128*256
  unsigned spin = idx >> 15;
  unsigned rem = idx & 32767u;
  unsigned b = rem >> 8;
  unsigned k4 = (rem & 255u) << 2;
  float4 v;
  if (k4 < 512u) {
    v = *(const float4*)(x + (size_t)b * 512 + k4);
  } else {
    v = *(const float4*)(x + (size_t)b * 512 + k4 - 512);
    if (spin) { v.x = -v.x; v.y = -v.y; v.z = -v.z; v.w = -v.w; }
  }
  store_bf4(xs + (size_t)spin * (NB * NGRU) + (size_t)b * NGRU + k4, v.x, v.y, v.z, v.w);
}

// ---------- prep: biases ----------
__global__ void prep_bias(const float* __restrict__ biU, const float* __restrict__ bhU,
                          const float* __restrict__ biD, const float* __restrict__ bhD,
                          float* __restrict__ bias) {
  unsigned idx = blockIdx.x * 256u + threadIdx.x;  // < 8192
  unsigned wset = idx >> 12;
  unsigned g = (idx >> 10) & 3u;
  unsigned r = idx & 1023u;
  const float* bi = wset ? biD : biU;
  const float* bh = wset ? bhD : bhU;
  float v;
  if (g == 0u)      v = bi[r] + bh[r];
  else if (g == 1u) v = bi[1024u + r] + bh[1024u + r];
  else if (g == 2u) v = bi[2048u + r];
  else              v = bh[2048u + r];
  bias[idx] = v;
}

// ---------- main persistent GRU kernel ----------
// 256 blocks: seq = bid>>6 (wset=seq>>1, spin=seq&1), ctile = bid&63 (16 cols)
// 4 waves: K-split (wave*256..+256). Wave-tile = full 128M x 64effN.
__global__ __launch_bounds__(256, 1) void gru_main(
    const u16* __restrict__ Wih, const u16* __restrict__ Wfu,
    const float* __restrict__ bias, const u16* __restrict__ xs,
    u16* __restrict__ hbf, float* __restrict__ out, u32* __restrict__ bars) {
  __shared__ floatx4 red[3072];  // 48KB reduction buffer

  const int tid = threadIdx.x;
  const int wave = tid >> 6, lane = tid & 63;
  const int fr = lane & 15, fq = lane >> 4;
  const int bid = blockIdx.x;
  const int seq = bid >> 6, ctile = bid & 63;
  const int wset = seq >> 1, spin = seq & 1;
  const int col0 = ctile << 4;

  // persistent register-resident B: Breg[kstep][gate], step-0 version first
  shortx8 Breg[8][4];
  {
    const u16* w0 = Wih + (size_t)wset * 3072 * NGRU;
    const shortx8 bz = {0, 0, 0, 0, 0, 0, 0, 0};
#pragma unroll
    for (int ks = 0; ks < 8; ++ks) {
#pragma unroll
      for (int nf = 0; nf < 4; ++nf) {
        if (nf == 3) {
          Breg[ks][nf] = bz;  // h_n has no matmul at t=0 (h==0)
        } else {
          Breg[ks][nf] = *reinterpret_cast<const shortx8*>(
              w0 + (size_t)(nf * NGRU + col0 + fr) * NGRU + wave * 256 + ks * 32 + fq * 8);
        }
      }
    }
  }

  const float bR = bias[wset * 4096 + 0 * NGRU + col0 + fr];
  const float bZ = bias[wset * 4096 + 1 * NGRU + col0 + fr];
  const float bI = bias[wset * 4096 + 2 * NGRU + col0 + fr];
  const float bH = bias[wset * 4096 + 3 * NGRU + col0 + fr];

  float hown[2][4] = {{0.f, 0.f, 0.f, 0.f}, {0.f, 0.f, 0.f, 0.f}};
  u32* bar = bars + seq * 32;

#pragma unroll 1
  for (int t = 0; t < NSTEPS; ++t) {
    const u16* Ab = (t == 0) ? (xs + (size_t)spin * (NB * NGRU))
                             : (hbf + (size_t)(seq * 2 + (t & 1)) * (NB * NGRU));
    const u16* Arow = Ab + fr * NGRU + wave * 256 + fq * 8;

    floatx4 acc[8][4];
    const floatx4 fz = {0.f, 0.f, 0.f, 0.f};
#pragma unroll
    for (int mf = 0; mf < 8; ++mf)
#pragma unroll
      for (int nf = 0; nf < 4; ++nf) acc[mf][nf] = fz;

    // triple-buffered A fragments (2-deep prefetch over L2 latency)
    shortx8 ab[3][8];
#pragma unroll
    for (int mf = 0; mf < 8; ++mf)
      ab[0][mf] = *reinterpret_cast<const shortx8*>(Arow + mf * (16 * NGRU) + 0 * 32);
#pragma unroll
    for (int mf = 0; mf < 8; ++mf)
      ab[1][mf] = *reinterpret_cast<const shortx8*>(Arow + mf * (16 * NGRU) + 1 * 32);

#pragma unroll
    for (int ks = 0; ks < 8; ++ks) {
      if (ks < 6) {
#pragma unroll
        for (int mf = 0; mf < 8; ++mf)
          ab[(ks + 2) % 3][mf] =
              *reinterpret_cast<const shortx8*>(Arow + mf * (16 * NGRU) + (ks + 2) * 32);
      }
#pragma unroll
      for (int mf = 0; mf < 8; ++mf) {
#pragma unroll
        for (int nf = 0; nf < 4; ++nf) {
          acc[mf][nf] = __builtin_amdgcn_mfma_f32_16x16x32_bf16(
              ab[ks % 3][mf], Breg[ks][nf], acc[mf][nf], 0, 0, 0);
        }
      }
    }

    // after step 0's MFMAs, swap to fused weights (overlaps with reduction below)
    if (t == 0) {
      const u16* wf = Wfu + (size_t)wset * 4096 * NGRU;
#pragma unroll
      for (int ks = 0; ks < 8; ++ks)
#pragma unroll
        for (int nf = 0; nf < 4; ++nf)
          Breg[ks][nf] = *reinterpret_cast<const shortx8*>(
              wf + (size_t)(nf * NGRU + col0 + fr) * NGRU + wave * 256 + ks * 32 + fq * 8);
    }

    // cross-wave K reduction: 2 super-phases of 4 Mfrags; owner(mf) = mf>>1
#pragma unroll
    for (int sp = 0; sp < 2; ++sp) {
#pragma unroll
      for (int i = 0; i < 4; ++i) {
        const int mf = sp * 4 + i;
        const int owner = mf >> 1;
        if (wave != owner) {
          const int slot = wave - (wave > owner ? 1 : 0);
#pragma unroll
          for (int nf = 0; nf < 4; ++nf)
            red[((i * 3 + slot) * 4 + nf) * 64 + lane] = acc[mf][nf];
        }
      }
      __syncthreads();
#pragma unroll
      for (int i = 0; i < 4; ++i) {
        const int mf = sp * 4 + i;
        if (wave == (mf >> 1)) {
#pragma unroll
          for (int slot = 0; slot < 3; ++slot)
#pragma unroll
            for (int nf = 0; nf < 4; ++nf)
              acc[mf][nf] += red[((i * 3 + slot) * 4 + nf) * 64 + lane];
        }
      }
      __syncthreads();
    }

    // epilogue: wave owns Mfrags {2*wave, 2*wave+1}
    float* outp = out + (size_t)seq * (NB * NSTEPS * NGRU) + (size_t)t * NGRU + col0 + fr;
    u16* hw = hbf + (size_t)(seq * 2 + ((t + 1) & 1)) * (NB * NGRU) + col0 + fr;
#pragma unroll
    for (int mf = 0; mf < 8; ++mf) {
      if ((mf >> 1) == wave) {
        const int sub = mf & 1;
#pragma unroll
        for (int j = 0; j < 4; ++j) {
          const float r = sigm_f(acc[mf][0][j] + bR);
          const float z = sigm_f(acc[mf][1][j] + bZ);
          const float n = tanh_f(acc[mf][2][j] + bI + r * (acc[mf][3][j] + bH));
          const float hv = (1.0f - z) * n + z * hown[sub][j];
          hown[sub][j] = hv;
          const int row = mf * 16 + fq * 4 + j;
          __builtin_nontemporal_store(hv, outp + (size_t)row * (NSTEPS * NGRU));
          __hip_bfloat16 hb = __float2bfloat16(hv);
          hw[row * NGRU] = *reinterpret_cast<u16*>(&hb);
        }
      }
    }

    // per-sequence device barrier (64 blocks)
    if (t < NSTEPS - 1) {
      __syncthreads();  // drains vmcnt: all stores of this block are globally issued
      if (tid == 0) {
        __threadfence();  // agent release: wb L2 so other XCDs can see h
        __hip_atomic_fetch_add(bar, 1u, __ATOMIC_RELAXED, __HIP_MEMORY_SCOPE_AGENT);
        const u32 target = 64u * (u32)(t + 1);
        while (__hip_atomic_load(bar, __ATOMIC_RELAXED, __HIP_MEMORY_SCOPE_AGENT) < target) {
          __builtin_amdgcn_s_sleep(1);
        }
        __threadfence();  // agent acquire: invalidate stale L1/L2 lines
      }
      __syncthreads();
    }
  }
}

extern "C" void kernel_launch(void* const* d_in, const int* in_sizes, int n_in,
                              void* d_out, int out_size, void* d_ws, size_t ws_size,
                              hipStream_t stream) {
  const float* x    = (const float*)d_in[0];
  const float* ihU  = (const float*)d_in[1];
  const float* hhU  = (const float*)d_in[2];
  const float* ihD  = (const float*)d_in[3];
  const float* hhD  = (const float*)d_in[4];
  const float* biU  = (const float*)d_in[5];
  const float* bhU  = (const float*)d_in[6];
  const float* biD  = (const float*)d_in[7];
  const float* bhD  = (const float*)d_in[8];

  char* ws = (char*)d_ws;
  __hip_bfloat16* Wih_b = (__hip_bfloat16*)(ws + WS_W0);
  __hip_bfloat16* Wf_b  = (__hip_bfloat16*)(ws + WS_WF);
  float* bias           = (float*)(ws + WS_BIAS);
  __hip_bfloat16* xs    = (__hip_bfloat16*)(ws + WS_XS);
  u16* hbf              = (u16*)(ws + WS_HBF);
  u32* bars             = (u32*)(ws + WS_BARS);

  (void)hipMemsetAsync(bars, 0, 512, stream);
  prep_w<<<8192, 256, 0, stream>>>(ihU, hhU, ihD, hhD, Wih_b, Wf_b);
  prep_x<<<256, 256, 0, stream>>>(x, xs);
  prep_bias<<<32, 256, 0, stream>>>(biU, bhU, biD, bhD, bias);
  gru_main<<<256, 256, 0, stream>>>((const u16*)Wih_b, (const u16*)Wf_b, bias,
                                    (const u16*)xs, hbf, (float*)d_out, bars);
}

// Round 3
// 5374.752 us; speedup vs baseline: 1.9104x; 1.9104x over previous
//
#include <hip/hip_runtime.h>
#include <hip/hip_bf16.h>

typedef __attribute__((ext_vector_type(8))) short shortx8;
typedef __attribute__((ext_vector_type(4))) float floatx4;
typedef unsigned short u16;
typedef unsigned int u32;

#define NGRU 1024
#define NB 128
#define NSTEPS 256

// ---- ws layout (bytes) ----
#define WS_W0   0u           // Wih bf16  [2][3072][1024]
#define WS_WF   12582912u    // fused bf16 [2][4096][1024] (rz fused, in=Wih_n, hn=Whh_n)
#define WS_BIAS 29360128u    // fp32 [2][4][1024]
#define WS_XS   29392896u    // x_spin bf16 [2][128][1024]
#define WS_HBF  29917184u    // h bf16 [4 seq][2 buf][128][1024]
#define WS_BARS 32014336u    // 4 counters, 128B apart

__device__ __forceinline__ float sigm_f(float x) {
  return 1.0f / (1.0f + __expf(-x));
}
__device__ __forceinline__ float tanh_f(float x) {
  float e = __expf(-2.0f * fabsf(x));
  float t = (1.0f - e) / (1.0f + e);
  return copysignf(t, x);
}
__device__ __forceinline__ void store_bf4(__hip_bfloat16* dst, float a, float b, float c, float d) {
  __hip_bfloat16 t[4] = {__float2bfloat16(a), __float2bfloat16(b),
                         __float2bfloat16(c), __float2bfloat16(d)};
  *reinterpret_cast<uint2*>(dst) = *reinterpret_cast<uint2*>(t);
}

// device-coherent 16B load (bypasses stale L1/L2, reads from coherence point)
__device__ __forceinline__ void loada_dc(shortx8& dst, const u16* p) {
  asm volatile("global_load_dwordx4 %0, %1, off sc0 sc1" : "=v"(dst) : "v"(p));
}
// device-coherent 2B store (write-through to coherence point)
__device__ __forceinline__ void storeh_dc(u16* p, u32 bits) {
  asm volatile("global_store_short %0, %1, off sc0 sc1" :: "v"(p), "v"(bits) : "memory");
}

// ---------- prep: weights -> bf16 (plain Wih + fused) ----------
__global__ void prep_w(const float* __restrict__ ihU, const float* __restrict__ hhU,
                       const float* __restrict__ ihD, const float* __restrict__ hhD,
                       __hip_bfloat16* __restrict__ Wih_b, __hip_bfloat16* __restrict__ Wf_b) {
  unsigned idx = blockIdx.x * 256u + threadIdx.x;   // < 2*4096*256
  unsigned wset = idx >> 20;
  unsigned rem = idx & 1048575u;
  unsigned j = rem >> 8;                 // row 0..4095 (gate-major: r,z,in,hn)
  unsigned k4 = (rem & 255u) << 2;       // k 0..1020 step 4
  const float* ih = wset ? ihD : ihU;
  const float* hh = wset ? hhD : hhU;
  unsigned g = j >> 10, r = j & 1023u;
  if (j < 3072u) {
    const float* pa = ih + (size_t)j * NGRU + k4;
    float4 a = *(const float4*)pa;
    store_bf4(Wih_b + (size_t)wset * 3072 * NGRU + (size_t)j * NGRU + k4, a.x, a.y, a.z, a.w);
    float fx = a.x, fy = a.y, fz = a.z, fw = a.w;
    if (g < 2u) {
      const float* pb = hh + (size_t)j * NGRU + k4;
      float4 b = *(const float4*)pb;
      fx += b.x; fy += b.y; fz += b.z; fw += b.w;
    }
    store_bf4(Wf_b + (size_t)wset * 4096 * NGRU + (size_t)j * NGRU + k4, fx, fy, fz, fw);
  } else {
    const float* pb = hh + (size_t)(2048u + r) * NGRU + k4;
    float4 b = *(const float4*)pb;
    store_bf4(Wf_b + (size_t)wset * 4096 * NGRU + (size_t)j * NGRU + k4, b.x, b.y, b.z, b.w);
  }
}

// ---------- prep: x_spin -> bf16 ----------
__global__ void prep_x(const float* __restrict__ x, __hip_bfloat16* __restrict__ xs) {
  unsigned idx = blockIdx.x * 256u + threadIdx.x;   // < 2*128*256
  unsigned spin = idx >> 15;
  unsigned rem = idx & 32767u;
  unsigned b = rem >> 8;
  unsigned k4 = (rem & 255u) << 2;
  float4 v;
  if (k4 < 512u) {
    v = *(const float4*)(x + (size_t)b * 512 + k4);
  } else {
    v = *(const float4*)(x + (size_t)b * 512 + k4 - 512);
    if (spin) { v.x = -v.x; v.y = -v.y; v.z = -v.z; v.w = -v.w; }
  }
  store_bf4(xs + (size_t)spin * (NB * NGRU) + (size_t)b * NGRU + k4, v.x, v.y, v.z, v.w);
}

// ---------- prep: biases ----------
__global__ void prep_bias(const float* __restrict__ biU, const float* __restrict__ bhU,
                          const float* __restrict__ biD, const float* __restrict__ bhD,
                          float* __restrict__ bias) {
  unsigned idx = blockIdx.x * 256u + threadIdx.x;  // < 8192
  unsigned wset = idx >> 12;
  unsigned g = (idx >> 10) & 3u;
  unsigned r = idx & 1023u;
  const float* bi = wset ? biD : biU;
  const float* bh = wset ? bhD : bhU;
  float v;
  if (g == 0u)      v = bi[r] + bh[r];
  else if (g == 1u) v = bi[1024u + r] + bh[1024u + r];
  else if (g == 2u) v = bi[2048u + r];
  else              v = bh[2048u + r];
  bias[idx] = v;
}

// ---------- main persistent GRU kernel ----------
// 256 blocks: seq = bid>>6 (wset=seq>>1, spin=seq&1), ctile = bid&63 (16 cols)
// 4 waves: K-split (wave*256..+256). Wave-tile = full 128M x 64effN.
// h coherence: sc0sc1 loads/stores only (NO whole-L2 wbl2/inv fences).
__global__ __launch_bounds__(256, 1) void gru_main(
    const u16* __restrict__ Wih, const u16* __restrict__ Wfu,
    const float* __restrict__ bias, const u16* __restrict__ xs,
    u16* __restrict__ hbf, float* __restrict__ out, u32* __restrict__ bars) {
  __shared__ floatx4 red[3072];  // 48KB reduction buffer

  const int tid = threadIdx.x;
  const int wave = tid >> 6, lane = tid & 63;
  const int fr = lane & 15, fq = lane >> 4;
  const int bid = blockIdx.x;
  const int seq = bid >> 6, ctile = bid & 63;
  const int wset = seq >> 1, spin = seq & 1;
  const int col0 = ctile << 4;

  // persistent register-resident B: Breg[kstep][gate], step-0 version first
  shortx8 Breg[8][4];
  {
    const u16* w0 = Wih + (size_t)wset * 3072 * NGRU;
    const shortx8 bz = {0, 0, 0, 0, 0, 0, 0, 0};
#pragma unroll
    for (int ks = 0; ks < 8; ++ks) {
#pragma unroll
      for (int nf = 0; nf < 4; ++nf) {
        if (nf == 3) {
          Breg[ks][nf] = bz;  // h_n has no matmul at t=0 (h==0)
        } else {
          Breg[ks][nf] = *reinterpret_cast<const shortx8*>(
              w0 + (size_t)(nf * NGRU + col0 + fr) * NGRU + wave * 256 + ks * 32 + fq * 8);
        }
      }
    }
  }

  const float bR = bias[wset * 4096 + 0 * NGRU + col0 + fr];
  const float bZ = bias[wset * 4096 + 1 * NGRU + col0 + fr];
  const float bI = bias[wset * 4096 + 2 * NGRU + col0 + fr];
  const float bH = bias[wset * 4096 + 3 * NGRU + col0 + fr];

  float hown[2][4] = {{0.f, 0.f, 0.f, 0.f}, {0.f, 0.f, 0.f, 0.f}};
  u32* bar = bars + seq * 32;

#pragma unroll 1
  for (int t = 0; t < NSTEPS; ++t) {
    const u16* Ab = (t == 0) ? (xs + (size_t)spin * (NB * NGRU))
                             : (hbf + (size_t)(seq * 2 + (t & 1)) * (NB * NGRU));
    const u16* Arow = Ab + fr * NGRU + wave * 256 + fq * 8;

    // per-mf base pointers
    const u16* amf[8];
#pragma unroll
    for (int mf = 0; mf < 8; ++mf) amf[mf] = Arow + mf * (16 * NGRU);

    floatx4 acc[8][4];
    const floatx4 fz = {0.f, 0.f, 0.f, 0.f};
#pragma unroll
    for (int mf = 0; mf < 8; ++mf)
#pragma unroll
      for (int nf = 0; nf < 4; ++nf) acc[mf][nf] = fz;

    // triple-buffered A fragments, device-coherent asm loads, counted vmcnt
    shortx8 ab[3][8];
#pragma unroll
    for (int mf = 0; mf < 8; ++mf) loada_dc(ab[0][mf], amf[mf] + 0 * 32);
#pragma unroll
    for (int mf = 0; mf < 8; ++mf) loada_dc(ab[1][mf], amf[mf] + 1 * 32);

#pragma unroll
    for (int ks = 0; ks < 8; ++ks) {
      if (ks < 6) {
#pragma unroll
        for (int mf = 0; mf < 8; ++mf)
          loada_dc(ab[(ks + 2) % 3][mf], amf[mf] + (ks + 2) * 32);
      }
      // wait until the group for this ks has landed (2 groups may stay in flight)
      if (ks < 6)      asm volatile("s_waitcnt vmcnt(16)" ::: "memory");
      else if (ks == 6) asm volatile("s_waitcnt vmcnt(8)" ::: "memory");
      else              asm volatile("s_waitcnt vmcnt(0)" ::: "memory");
      __builtin_amdgcn_sched_barrier(0);
#pragma unroll
      for (int mf = 0; mf < 8; ++mf) {
#pragma unroll
        for (int nf = 0; nf < 4; ++nf) {
          acc[mf][nf] = __builtin_amdgcn_mfma_f32_16x16x32_bf16(
              ab[ks % 3][mf], Breg[ks][nf], acc[mf][nf], 0, 0, 0);
        }
      }
    }

    // after step 0's MFMAs, swap to fused weights (overlaps with reduction below)
    if (t == 0) {
      const u16* wf = Wfu + (size_t)wset * 4096 * NGRU;
#pragma unroll
      for (int ks = 0; ks < 8; ++ks)
#pragma unroll
        for (int nf = 0; nf < 4; ++nf)
          Breg[ks][nf] = *reinterpret_cast<const shortx8*>(
              wf + (size_t)(nf * NGRU + col0 + fr) * NGRU + wave * 256 + ks * 32 + fq * 8);
    }

    // cross-wave K reduction: 2 super-phases of 4 Mfrags; owner(mf) = mf>>1
#pragma unroll
    for (int sp = 0; sp < 2; ++sp) {
#pragma unroll
      for (int i = 0; i < 4; ++i) {
        const int mf = sp * 4 + i;
        const int owner = mf >> 1;
        if (wave != owner) {
          const int slot = wave - (wave > owner ? 1 : 0);
#pragma unroll
          for (int nf = 0; nf < 4; ++nf)
            red[((i * 3 + slot) * 4 + nf) * 64 + lane] = acc[mf][nf];
        }
      }
      __syncthreads();
#pragma unroll
      for (int i = 0; i < 4; ++i) {
        const int mf = sp * 4 + i;
        if (wave == (mf >> 1)) {
#pragma unroll
          for (int slot = 0; slot < 3; ++slot)
#pragma unroll
            for (int nf = 0; nf < 4; ++nf)
              acc[mf][nf] += red[((i * 3 + slot) * 4 + nf) * 64 + lane];
        }
      }
      __syncthreads();
    }

    // epilogue: wave owns Mfrags {2*wave, 2*wave+1}
    float* outp = out + (size_t)seq * (NB * NSTEPS * NGRU) + (size_t)t * NGRU + col0 + fr;
    u16* hw = hbf + (size_t)(seq * 2 + ((t + 1) & 1)) * (NB * NGRU) + col0 + fr;
#pragma unroll
    for (int mf = 0; mf < 8; ++mf) {
      if ((mf >> 1) == wave) {
        const int sub = mf & 1;
#pragma unroll
        for (int j = 0; j < 4; ++j) {
          const float r = sigm_f(acc[mf][0][j] + bR);
          const float z = sigm_f(acc[mf][1][j] + bZ);
          const float n = tanh_f(acc[mf][2][j] + bI + r * (acc[mf][3][j] + bH));
          const float hv = (1.0f - z) * n + z * hown[sub][j];
          hown[sub][j] = hv;
          const int row = mf * 16 + fq * 4 + j;
          __builtin_nontemporal_store(hv, outp + (size_t)row * (NSTEPS * NGRU));
          __hip_bfloat16 hb = __float2bfloat16(hv);
          storeh_dc(hw + (size_t)row * NGRU, (u32)*reinterpret_cast<u16*>(&hb));
        }
      }
    }

    // per-sequence device barrier (64 blocks). Release = per-wave vmcnt(0) drain
    // of the sc0sc1 write-through h stores; no L2 flush/invalidate needed since
    // all h traffic is device-coherent.
    if (t < NSTEPS - 1) {
      asm volatile("s_waitcnt vmcnt(0)" ::: "memory");
      __builtin_amdgcn_sched_barrier(0);
      __syncthreads();
      if (tid == 0) {
        __hip_atomic_fetch_add(bar, 1u, __ATOMIC_RELAXED, __HIP_MEMORY_SCOPE_AGENT);
        const u32 target = 64u * (u32)(t + 1);
        while (__hip_atomic_load(bar, __ATOMIC_RELAXED, __HIP_MEMORY_SCOPE_AGENT) < target) {
          __builtin_amdgcn_s_sleep(1);
        }
      }
      __syncthreads();
    }
  }
}

extern "C" void kernel_launch(void* const* d_in, const int* in_sizes, int n_in,
                              void* d_out, int out_size, void* d_ws, size_t ws_size,
                              hipStream_t stream) {
  const float* x    = (const float*)d_in[0];
  const float* ihU  = (const float*)d_in[1];
  const float* hhU  = (const float*)d_in[2];
  const float* ihD  = (const float*)d_in[3];
  const float* hhD  = (const float*)d_in[4];
  const float* biU  = (const float*)d_in[5];
  const float* bhU  = (const float*)d_in[6];
  const float* biD  = (const float*)d_in[7];
  const float* bhD  = (const float*)d_in[8];

  char* ws = (char*)d_ws;
  __hip_bfloat16* Wih_b = (__hip_bfloat16*)(ws + WS_W0);
  __hip_bfloat16* Wf_b  = (__hip_bfloat16*)(ws + WS_WF);
  float* bias           = (float*)(ws + WS_BIAS);
  __hip_bfloat16* xs    = (__hip_bfloat16*)(ws + WS_XS);
  u16* hbf              = (u16*)(ws + WS_HBF);
  u32* bars             = (u32*)(ws + WS_BARS);

  (void)hipMemsetAsync(bars, 0, 512, stream);
  prep_w<<<8192, 256, 0, stream>>>(ihU, hhU, ihD, hhD, Wih_b, Wf_b);
  prep_x<<<256, 256, 0, stream>>>(x, xs);
  prep_bias<<<32, 256, 0, stream>>>(biU, bhU, biD, bhD, bias);
  gru_main<<<256, 256, 0, stream>>>((const u16*)Wih_b, (const u16*)Wf_b, bias,
                                    (const u16*)xs, hbf, (float*)d_out, bars);
}